// Round 1
// baseline (698.977 us; speedup 1.0000x reference)
//
#include <hip/hip_runtime.h>

#define NN 12288
#define DD 128

// One block per output row i.
// Phase 1: zero the 48 KB row with coalesced float4 stores (+ stage z1[i] in LDS).
// Phase 2 (after barrier): fill the ~9.5 same-(graph,class) entries with fp32 dots.
// batch[] is sorted, so the same-graph range is found by binary search.
__global__ __launch_bounds__(256) void segdec_kernel(
    const float* __restrict__ z1, const float* __restrict__ z2,
    const int* __restrict__ cls, const int* __restrict__ batch,
    float* __restrict__ out)
{
    const int i   = blockIdx.x;
    const int tid = threadIdx.x;
    __shared__ float z1s[DD];

    // stage z1 row (512 B) into LDS
    if (tid < DD / 4) {
        reinterpret_cast<float4*>(z1s)[tid] =
            reinterpret_cast<const float4*>(z1 + (size_t)i * DD)[tid];
    }

    // zero this row: 3072 float4 / 256 threads = 12 stores each, fully coalesced
    const float4 zero4 = make_float4(0.f, 0.f, 0.f, 0.f);
    float4* __restrict__ orow = reinterpret_cast<float4*>(out + (size_t)i * NN);
    #pragma unroll
    for (int k = 0; k < (NN / 4) / 256; ++k) {
        orow[tid + k * 256] = zero4;
    }

    const int batch_i = batch[i];
    const int cls_i   = cls[i];

    // __syncthreads lowers to s_waitcnt vmcnt(0) + s_barrier: zero-stores are
    // drained before any post-barrier store to the same row can issue.
    __syncthreads();

    if (cls_i >= 24) return;   // excluded classes: row stays all-zero

    // binary search [lo, hi) = indices with batch[] == batch_i (batch sorted)
    int lo, hi;
    {
        int l = 0, r = NN;
        while (l < r) { int m = (l + r) >> 1; if (batch[m] < batch_i) l = m + 1; else r = m; }
        lo = l;
        r = NN;
        while (l < r) { int m = (l + r) >> 1; if (batch[m] <= batch_i) l = m + 1; else r = m; }
        hi = l;
    }

    // ~256 candidates, ~9.5 matches per row; matched lanes do a 128-wide dot.
    for (int j = lo + tid; j < hi; j += 256) {
        if (j != i && cls[j] == cls_i) {
            const float4* __restrict__ zrow =
                reinterpret_cast<const float4*>(z2 + (size_t)j * DD);
            float s = 0.f;
            #pragma unroll
            for (int k = 0; k < DD / 4; ++k) {
                const float4 a = reinterpret_cast<const float4*>(z1s)[k];
                const float4 b = zrow[k];
                s = fmaf(a.x, b.x, s);
                s = fmaf(a.y, b.y, s);
                s = fmaf(a.z, b.z, s);
                s = fmaf(a.w, b.w, s);
            }
            out[(size_t)i * NN + j] = s;
        }
    }
}

extern "C" void kernel_launch(void* const* d_in, const int* in_sizes, int n_in,
                              void* d_out, int out_size, void* d_ws, size_t ws_size,
                              hipStream_t stream) {
    const float* z1    = (const float*)d_in[0];
    const float* z2    = (const float*)d_in[1];
    const int*   cls   = (const int*)d_in[2];
    const int*   batch = (const int*)d_in[3];
    float*       out   = (float*)d_out;

    segdec_kernel<<<NN, 256, 0, stream>>>(z1, z2, cls, batch, out);
}

// Round 2
// 672.976 us; speedup vs baseline: 1.0386x; 1.0386x over previous
//
#include <hip/hip_runtime.h>

#define NN 12288
#define DD 128

// ---------------------------------------------------------------------------
// Kernel 1: pure zero-fill of the 604 MB output, grid-stride float4 streamer.
// Mirrors rocclr fillBuffer (measured 6.1-6.25 TB/s on this device). No
// barriers, no divergence: 37,748,736 float4 / (1024*256) = exactly 144/thread.
// ---------------------------------------------------------------------------
__global__ __launch_bounds__(256) void zero_fill(float4* __restrict__ out) {
    const size_t total  = (size_t)NN * NN / 4;
    const size_t stride = (size_t)gridDim.x * blockDim.x;
    const float4 z = make_float4(0.f, 0.f, 0.f, 0.f);
    for (size_t idx = (size_t)blockIdx.x * blockDim.x + threadIdx.x;
         idx < total; idx += stride) {
        out[idx] = z;
    }
}

// ---------------------------------------------------------------------------
// Kernel 2: sparse fill. One wave per row i; ~256 same-graph candidates,
// ~9.5 class matches per row. z1 row staged in LDS (same-address broadcast
// reads are conflict-free). batch[] sorted -> binary search graph range.
// Runs after zero_fill on the same stream (kernel boundary = WAW ordering).
// ---------------------------------------------------------------------------
__global__ __launch_bounds__(256) void sparse_fill(
    const float* __restrict__ z1, const float* __restrict__ z2,
    const int* __restrict__ cls, const int* __restrict__ batch,
    float* __restrict__ out)
{
    const int wave = threadIdx.x >> 6;          // 0..3
    const int lane = threadIdx.x & 63;
    const int i    = blockIdx.x * 4 + wave;     // row handled by this wave

    __shared__ float z1s[4][DD];
    // 256 threads cooperatively load 4 rows x 128 floats = 512 floats (float2 each)
    {
        const float2* src =
            reinterpret_cast<const float2*>(z1 + (size_t)blockIdx.x * 4 * DD);
        reinterpret_cast<float2*>(&z1s[0][0])[threadIdx.x] = src[threadIdx.x];
    }
    __syncthreads();

    const int cls_i = cls[i];
    if (cls_i >= 24) return;                    // excluded classes: row stays zero
    const int batch_i = batch[i];

    // binary search [lo, hi) = same-graph index range (batch sorted)
    int lo, hi;
    {
        int l = 0, r = NN;
        while (l < r) { int m = (l + r) >> 1; if (batch[m] <  batch_i) l = m + 1; else r = m; }
        lo = l;
        r = NN;
        while (l < r) { int m = (l + r) >> 1; if (batch[m] <= batch_i) l = m + 1; else r = m; }
        hi = l;
    }

    for (int j = lo + lane; j < hi; j += 64) {
        if (j != i && cls[j] == cls_i) {
            const float4* __restrict__ zb =
                reinterpret_cast<const float4*>(z2 + (size_t)j * DD);
            const float4* __restrict__ za =
                reinterpret_cast<const float4*>(&z1s[wave][0]);
            float s = 0.f;
            #pragma unroll
            for (int k = 0; k < DD / 4; ++k) {
                const float4 a = za[k];
                const float4 b = zb[k];
                s = fmaf(a.x, b.x, s);
                s = fmaf(a.y, b.y, s);
                s = fmaf(a.z, b.z, s);
                s = fmaf(a.w, b.w, s);
            }
            out[(size_t)i * NN + j] = s;
        }
    }
}

extern "C" void kernel_launch(void* const* d_in, const int* in_sizes, int n_in,
                              void* d_out, int out_size, void* d_ws, size_t ws_size,
                              hipStream_t stream) {
    const float* z1    = (const float*)d_in[0];
    const float* z2    = (const float*)d_in[1];
    const int*   cls   = (const int*)d_in[2];
    const int*   batch = (const int*)d_in[3];
    float*       out   = (float*)d_out;

    zero_fill<<<1024, 256, 0, stream>>>(reinterpret_cast<float4*>(out));
    sparse_fill<<<NN / 4, 256, 0, stream>>>(z1, z2, cls, batch, out);
}

// Round 3
// 666.382 us; speedup vs baseline: 1.0489x; 1.0099x over previous
//
#include <hip/hip_runtime.h>

#define NN 12288
#define DD 128

// Fused single-pass kernel: one block per output row i, 256 threads.
// Thread t owns float4 chunks {t + 256*k : k=0..11} of the row and writes each
// EXACTLY once with its final value: zero outside the same-graph band
// (~98% of chunks -> pure streaming store, fillBuffer-like), or a predicated
// dot(z1[i], z2[j]) inside the band. One writer per cell -> no barrier, no
// two-pass WAW, no RMW re-fetch of output lines.
__global__ __launch_bounds__(256) void segdec_fused(
    const float* __restrict__ z1, const float* __restrict__ z2,
    const int* __restrict__ cls, const int* __restrict__ batch,
    float* __restrict__ out)
{
    const int i   = blockIdx.x;
    const int tid = threadIdx.x;
    float4* __restrict__ orow = reinterpret_cast<float4*>(out + (size_t)i * NN);
    const float4 zero4 = make_float4(0.f, 0.f, 0.f, 0.f);

    const int cls_i = cls[i];
    if (cls_i >= 24) {
        // excluded class: whole row is zero — pure streaming path
        #pragma unroll
        for (int k = 0; k < 12; ++k) orow[tid + k * 256] = zero4;
        return;
    }

    // same-graph band [lo, hi): batch[] is sorted -> binary search.
    // Uniform across the block (blockIdx-derived) -> scalarizes.
    const int batch_i = batch[i];
    int lo, hi;
    {
        int l = 0, r = NN;
        while (l < r) { int m = (l + r) >> 1; if (batch[m] <  batch_i) l = m + 1; else r = m; }
        lo = l;
        r = NN;
        while (l < r) { int m = (l + r) >> 1; if (batch[m] <= batch_i) l = m + 1; else r = m; }
        hi = l;
    }

    const float4* __restrict__ za = reinterpret_cast<const float4*>(z1 + (size_t)i * DD);

    for (int k = 0; k < 12; ++k) {
        const int f4 = tid + k * 256;
        const int c0 = f4 * 4;                 // first column of this chunk
        float4 v = zero4;
        if (c0 < hi && c0 + 4 > lo) {          // chunk overlaps the band (rare)
            float vv[4] = {0.f, 0.f, 0.f, 0.f};
            #pragma unroll
            for (int u = 0; u < 4; ++u) {
                const int j = c0 + u;
                if (j >= lo && j < hi && j != i && cls[j] == cls_i) {
                    const float4* __restrict__ zb =
                        reinterpret_cast<const float4*>(z2 + (size_t)j * DD);
                    float s = 0.f;
                    #pragma unroll
                    for (int d = 0; d < DD / 4; ++d) {
                        const float4 a = za[d];
                        const float4 b = zb[d];
                        s = fmaf(a.x, b.x, s);
                        s = fmaf(a.y, b.y, s);
                        s = fmaf(a.z, b.z, s);
                        s = fmaf(a.w, b.w, s);
                    }
                    vv[u] = s;
                }
            }
            v = make_float4(vv[0], vv[1], vv[2], vv[3]);
        }
        orow[f4] = v;
    }
}

extern "C" void kernel_launch(void* const* d_in, const int* in_sizes, int n_in,
                              void* d_out, int out_size, void* d_ws, size_t ws_size,
                              hipStream_t stream) {
    const float* z1    = (const float*)d_in[0];
    const float* z2    = (const float*)d_in[1];
    const int*   cls   = (const int*)d_in[2];
    const int*   batch = (const int*)d_in[3];
    float*       out   = (float*)d_out;

    segdec_fused<<<NN, 256, 0, stream>>>(z1, z2, cls, batch, out);
}

// Round 4
// 642.859 us; speedup vs baseline: 1.0873x; 1.0366x over previous
//
#include <hip/hip_runtime.h>

#define NN 12288
#define DD 128

typedef float v4f __attribute__((ext_vector_type(4)));

// Fused single-pass kernel: one block per output row i, 256 threads.
// Thread t owns float4 chunks {t + 256*k : k=0..11}; each cell is written
// exactly once. Changes vs R3:
//  - ALL pure-zero chunks are stored FIRST (store issue never stalls behind
//    the band dot chains), band chunks handled after via a bitmask.
//  - nontemporal stores: 604 MB is write-once -> don't allocate in L2.
__global__ __launch_bounds__(256) void segdec_fused(
    const float* __restrict__ z1, const float* __restrict__ z2,
    const int* __restrict__ cls, const int* __restrict__ batch,
    float* __restrict__ out)
{
    const int i   = blockIdx.x;
    const int tid = threadIdx.x;
    v4f* __restrict__ orow = reinterpret_cast<v4f*>(out + (size_t)i * NN);
    const v4f zero4 = {0.f, 0.f, 0.f, 0.f};

    const int cls_i = cls[i];
    if (cls_i >= 24) {
        // excluded class: whole row zero — pure nontemporal stream
        #pragma unroll
        for (int k = 0; k < 12; ++k)
            __builtin_nontemporal_store(zero4, &orow[tid + (k << 8)]);
        return;
    }

    // same-graph band [lo, hi): batch[] sorted -> binary search (block-uniform)
    const int batch_i = batch[i];
    int lo, hi;
    {
        int l = 0, r = NN;
        while (l < r) { int m = (l + r) >> 1; if (batch[m] <  batch_i) l = m + 1; else r = m; }
        lo = l;
        r = NN;
        while (l < r) { int m = (l + r) >> 1; if (batch[m] <= batch_i) l = m + 1; else r = m; }
        hi = l;
    }

    // Pass A: stream all non-band chunks (the overwhelming majority).
    unsigned band_mask = 0u;
    #pragma unroll
    for (int k = 0; k < 12; ++k) {
        const int f4 = tid + (k << 8);
        const int c0 = f4 << 2;
        if (c0 < hi && c0 + 4 > lo) {
            band_mask |= (1u << k);
        } else {
            __builtin_nontemporal_store(zero4, &orow[f4]);
        }
    }

    // Pass B: band chunks (~64 threads per block have exactly one).
    if (band_mask) {
        const v4f* __restrict__ za = reinterpret_cast<const v4f*>(z1 + (size_t)i * DD);
        while (band_mask) {
            const int k = __builtin_ctz(band_mask);
            band_mask &= band_mask - 1;
            const int f4 = tid + (k << 8);
            const int c0 = f4 << 2;
            float vv[4] = {0.f, 0.f, 0.f, 0.f};
            #pragma unroll
            for (int u = 0; u < 4; ++u) {
                const int j = c0 + u;
                if (j >= lo && j < hi && j != i && cls[j] == cls_i) {
                    const v4f* __restrict__ zb =
                        reinterpret_cast<const v4f*>(z2 + (size_t)j * DD);
                    float s = 0.f;
                    #pragma unroll
                    for (int d = 0; d < DD / 4; ++d) {
                        const v4f a = za[d];
                        const v4f b = zb[d];
                        s = fmaf(a.x, b.x, s);
                        s = fmaf(a.y, b.y, s);
                        s = fmaf(a.z, b.z, s);
                        s = fmaf(a.w, b.w, s);
                    }
                    vv[u] = s;
                }
            }
            const v4f v = {vv[0], vv[1], vv[2], vv[3]};
            __builtin_nontemporal_store(v, &orow[f4]);
        }
    }
}

extern "C" void kernel_launch(void* const* d_in, const int* in_sizes, int n_in,
                              void* d_out, int out_size, void* d_ws, size_t ws_size,
                              hipStream_t stream) {
    const float* z1    = (const float*)d_in[0];
    const float* z2    = (const float*)d_in[1];
    const int*   cls   = (const int*)d_in[2];
    const int*   batch = (const int*)d_in[3];
    float*       out   = (float*)d_out;

    segdec_fused<<<NN, 256, 0, stream>>>(z1, z2, cls, batch, out);
}